// Round 1
// baseline (103.326 us; speedup 1.0000x reference)
//
#include <hip/hip_runtime.h>

#define NUM_EXPERTS 64
#define TOP_K 2
#define NUM_TOKENS 16384
#define DIM 4096

// out[t, d] = x[t, d] * scores[t, 0] + x[t, d] * scores[t, 1]
// One block per token row. 256 threads x 4 float4 = 4096 floats = one row.
__global__ __launch_bounds__(256) void moe_scale_kernel(
    const float* __restrict__ x,
    const float* __restrict__ scores,
    float* __restrict__ out) {
    const int t = blockIdx.x;
    const float s0 = scores[t * TOP_K + 0];
    const float s1 = scores[t * TOP_K + 1];
    const float4* __restrict__ xin =
        reinterpret_cast<const float4*>(x + (size_t)t * DIM);
    float4* __restrict__ o = reinterpret_cast<float4*>(out + (size_t)t * DIM);
#pragma unroll
    for (int i = 0; i < 4; ++i) {
        const int idx = threadIdx.x + i * 256;
        float4 v = xin[idx];
        float4 r;
        r.x = v.x * s0 + v.x * s1;
        r.y = v.y * s0 + v.y * s1;
        r.z = v.z * s0 + v.z * s1;
        r.w = v.w * s0 + v.w * s1;
        o[idx] = r;
    }
}

// counts[e] = number of occurrences of e in the 32768 expert indices.
// Single block, 1024 threads, int4 loads, LDS atomics. Writes fresh floats
// every call (no dependence on prior d_out contents).
__global__ __launch_bounds__(1024) void moe_hist_kernel(
    const int* __restrict__ experts,
    float* __restrict__ counts) {
    __shared__ int h[NUM_EXPERTS];
    if (threadIdx.x < NUM_EXPERTS) h[threadIdx.x] = 0;
    __syncthreads();
    const int4* __restrict__ e4 = reinterpret_cast<const int4*>(experts);
    const int n4 = (NUM_TOKENS * TOP_K) / 4;  // 8192
    for (int i = threadIdx.x; i < n4; i += 1024) {
        int4 v = e4[i];
        atomicAdd(&h[v.x], 1);
        atomicAdd(&h[v.y], 1);
        atomicAdd(&h[v.z], 1);
        atomicAdd(&h[v.w], 1);
    }
    __syncthreads();
    if (threadIdx.x < NUM_EXPERTS) counts[threadIdx.x] = (float)h[threadIdx.x];
}

extern "C" void kernel_launch(void* const* d_in, const int* in_sizes, int n_in,
                              void* d_out, int out_size, void* d_ws, size_t ws_size,
                              hipStream_t stream) {
    const float* x = (const float*)d_in[0];
    const float* top_scores = (const float*)d_in[1];
    const int* experts = (const int*)d_in[2];
    // d_in[3] (num_tokens_per_expert) unused — reference overwrites it.

    float* out = (float*)d_out;                       // (NUM_TOKENS, DIM)
    float* counts = out + (size_t)NUM_TOKENS * DIM;   // (NUM_EXPERTS,)

    moe_scale_kernel<<<NUM_TOKENS, 256, 0, stream>>>(x, top_scores, out);
    moe_hist_kernel<<<1, 1024, 0, stream>>>(experts, counts);
}